// Round 3
// baseline (701.050 us; speedup 1.0000x reference)
//
#include <hip/hip_runtime.h>
#include <hip/hip_bf16.h>
#include <cstdint>
#include <cstddef>

#define N_NODES 10000
#define T_STEPS 6
#define F_IN    64
#define HID     64
#define HEADS   4
#define E_EDGES 160000
#define EP      (E_EDGES + N_NODES)   /* 170000 edges incl self-loops */
#define TN      (T_STEPS * N_NODES)   /* 60000 */

typedef __hip_bfloat16 bf16;

__device__ __forceinline__ float b2f(bf16 v) { return __bfloat162float(v); }

/* ---------------- CSR build ---------------- */

__global__ void k_init(int* counts, int* fill) {
    int i = blockIdx.x * blockDim.x + threadIdx.x;
    if (i < N_NODES) { counts[i] = 0; fill[i] = 0; }
}

__global__ void k_count(const int* ei, int* counts) {
    int e = blockIdx.x * blockDim.x + threadIdx.x;
    if (e >= EP) return;
    int dst = (e < E_EDGES) ? ei[E_EDGES + e] : (e - E_EDGES);
    atomicAdd(&counts[dst], 1);
}

__global__ void k_scan(const int* counts, int* rowstart) {
    __shared__ int part[1024];
    int tid = threadIdx.x;
    const int chunk = (N_NODES + 1023) / 1024;  // 10
    int base = tid * chunk;
    int s = 0;
    for (int i = 0; i < chunk; i++) { int idx = base + i; if (idx < N_NODES) s += counts[idx]; }
    part[tid] = s;
    __syncthreads();
    for (int off = 1; off < 1024; off <<= 1) {
        int v = (tid >= off) ? part[tid - off] : 0;
        __syncthreads();
        part[tid] += v;
        __syncthreads();
    }
    int run = (tid == 0) ? 0 : part[tid - 1];
    for (int i = 0; i < chunk; i++) {
        int idx = base + i;
        if (idx < N_NODES) { rowstart[idx] = run; run += counts[idx]; }
    }
    if (tid == 0) rowstart[N_NODES] = EP;
}

__global__ void k_scatter(const int* ei, const int* rowstart, int* fill,
                          int* csr_src) {
    int e = blockIdx.x * blockDim.x + threadIdx.x;
    if (e >= EP) return;
    int src = (e < E_EDGES) ? ei[e] : (e - E_EDGES);
    int dst = (e < E_EDGES) ? ei[E_EDGES + e] : (e - E_EDGES);
    int pos = rowstart[dst] + atomicAdd(&fill[dst], 1);
    csr_src[pos] = src;
}

/* ---------------- GAT layer 0 ---------------- */

/* X[60000,64] @ W0[64,64] -> XW0 (bf16), + fused per-row attention logits
   computed from the fp32 accumulator BEFORE bf16 rounding.
   256 threads = 4 rows x 64 cols; each wave handles exactly one row. */
__global__ __launch_bounds__(256) void k_gemm0(const float* __restrict__ x,
                                               const float* __restrict__ W0,
                                               const float* __restrict__ a_src0,
                                               const float* __restrict__ a_dst0,
                                               bf16* __restrict__ XW0b,
                                               float* __restrict__ ALS0,
                                               float* __restrict__ ALD0) {
    __shared__ float wl[64 * 64];
    __shared__ float xl[4][64];
    int tid = threadIdx.x;
    for (int i = tid; i < 4096; i += 256) wl[i] = W0[i];
    int r = tid >> 6, c = tid & 63;
    int row = blockIdx.x * 4 + r;            // row = t*N + n
    int t = row / N_NODES, n = row % N_NODES;
    xl[r][c] = x[(size_t)(n * T_STEPS + t) * F_IN + c];  // x is [N,T,F]
    __syncthreads();
    float acc = 0.f;
#pragma unroll
    for (int k = 0; k < 64; k++) acc += xl[r][k] * wl[k * 64 + c];
    XW0b[(size_t)row * 64 + c] = __float2bfloat16(acc);
    int h = c >> 4, cc = c & 15;
    float ps = acc * a_src0[h * 16 + cc];
    float pd = acc * a_dst0[h * 16 + cc];
#pragma unroll
    for (int o = 8; o; o >>= 1) { ps += __shfl_xor(ps, o, 64); pd += __shfl_xor(pd, o, 64); }
    if (cc == 0) { ALS0[row * 4 + h] = ps; ALD0[row * 4 + h] = pd; }
}

/* segment softmax stats: one thread per (t,n,h) */
__global__ void k_softmax(const int* __restrict__ rowstart, const int* __restrict__ csr_src,
                          const float* __restrict__ ALS, const float* __restrict__ ALD,
                          float* __restrict__ M, float* __restrict__ SI) {
    int idx = blockIdx.x * blockDim.x + threadIdx.x;
    if (idx >= TN * HEADS) return;
    int h = idx & 3;
    int tn = idx >> 2;
    int t = tn / N_NODES, n = tn % N_NODES;
    int rs = rowstart[n], re = rowstart[n + 1];
    float ald = ALD[tn * 4 + h];
    int tb = t * N_NODES;
    float m = -1e30f;
    for (int e = rs; e < re; e++) {
        int src = csr_src[e];
        float l = ALS[(tb + src) * 4 + h] + ald;
        l = l > 0.f ? l : 0.2f * l;
        m = fmaxf(m, l);
    }
    float s = 0.f;
    for (int e = rs; e < re; e++) {
        int src = csr_src[e];
        float l = ALS[(tb + src) * 4 + h] + ald;
        l = l > 0.f ? l : 0.2f * l;
        s += __expf(l - m);
    }
    M[idx] = m;
    SI[idx] = 1.f / (s + 1e-16f);
}

/* one wave per (t,dst): accumulate alpha-weighted neighbor rows, +bias, ELU */
__global__ __launch_bounds__(256) void k_accum0(const int* __restrict__ rowstart,
                                                const int* __restrict__ csr_src,
                                                const bf16* __restrict__ XW0b,
                                                const float* __restrict__ ALS0,
                                                const float* __restrict__ ALD0,
                                                const float* __restrict__ M,
                                                const float* __restrict__ SI,
                                                const float* __restrict__ b0,
                                                bf16* __restrict__ H0b) {
    int wid = blockIdx.x * 4 + (threadIdx.x >> 6);
    int lane = threadIdx.x & 63;
    if (wid >= TN) return;
    int t = wid / N_NODES, n = wid % N_NODES;
    int h = lane >> 4;
    float ald = ALD0[wid * 4 + h];
    float m = M[wid * 4 + h];
    float si = SI[wid * 4 + h];
    int rs = rowstart[n], re = rowstart[n + 1];
    int tb = t * N_NODES;
    float acc = 0.f;
    for (int e = rs; e < re; e++) {
        int src = csr_src[e];
        float l = ALS0[(tb + src) * 4 + h] + ald;
        l = l > 0.f ? l : 0.2f * l;
        float a = __expf(l - m) * si;
        acc += b2f(XW0b[(size_t)(tb + src) * 64 + lane]) * a;
    }
    float v = acc + b0[lane];
    v = v > 0.f ? v : (__expf(v) - 1.f);
    H0b[(size_t)wid * 64 + lane] = __float2bfloat16(v);
}

/* ---------------- GAT layer 1 ---------------- */

/* H0[60000,64] @ W1[64,256] -> XW1 (bf16, head-interleaved [cc][h] layout)
   + fused logits from the fp32 accumulator. 16 rows per block, W1 cached
   in LDS as bf16 (32 KB). */
__global__ __launch_bounds__(256) void k_gemm1(const bf16* __restrict__ H0b,
                                               const float* __restrict__ W1,
                                               const float* __restrict__ a_src1,
                                               const float* __restrict__ a_dst1,
                                               bf16* __restrict__ XW1b,
                                               float* __restrict__ ALS1,
                                               float* __restrict__ ALD1) {
    __shared__ bf16 wl[64 * 256];
    __shared__ float hl[16][64];
    int tid = threadIdx.x;
    for (int i = tid; i < 64 * 256; i += 256) wl[i] = __float2bfloat16(W1[i]);
    int rbase = blockIdx.x * 16;
    for (int i = tid; i < 16 * 64; i += 256)
        hl[i >> 6][i & 63] = b2f(H0b[((size_t)rbase + (i >> 6)) * 64 + (i & 63)]);
    __syncthreads();
    int h = tid >> 6, cc = tid & 63;
    float as = a_src1[h * 64 + cc], ad = a_dst1[h * 64 + cc];
    for (int r = 0; r < 16; r++) {
        float acc = 0.f;
#pragma unroll
        for (int k = 0; k < 64; k++) acc += hl[r][k] * b2f(wl[k * 256 + tid]);
        int row = rbase + r;
        /* head-interleaved store: row*256 + cc*4 + h */
        XW1b[(size_t)row * 256 + cc * 4 + h] = __float2bfloat16(acc);
        float ps = acc * as;
        float pd = acc * ad;
#pragma unroll
        for (int o = 32; o; o >>= 1) { ps += __shfl_xor(ps, o, 64); pd += __shfl_xor(pd, o, 64); }
        if (cc == 0) { ALS1[row * 4 + h] = ps; ALD1[row * 4 + h] = pd; }
    }
}

/* alpha output for t = T-1 only, in ORIGINAL edge order -> fp32 out */
__global__ void k_alpha_out(const int* __restrict__ ei,
                            const float* __restrict__ ALS1, const float* __restrict__ ALD1,
                            const float* __restrict__ M1, const float* __restrict__ SI1,
                            float* __restrict__ out_alpha) {
    int e = blockIdx.x * blockDim.x + threadIdx.x;
    if (e >= EP) return;
    int src = (e < E_EDGES) ? ei[e] : (e - E_EDGES);
    int dst = (e < E_EDGES) ? ei[E_EDGES + e] : (e - E_EDGES);
    const int tb = (T_STEPS - 1) * N_NODES;
    int sb = (tb + src) * 4, db = (tb + dst) * 4;
    float4 as = *(const float4*)(ALS1 + sb);
    float4 ad = *(const float4*)(ALD1 + db);
    float4 mm = *(const float4*)(M1 + db);
    float4 ss = *(const float4*)(SI1 + db);
    float l0 = as.x + ad.x; l0 = l0 > 0.f ? l0 : 0.2f * l0;
    float l1 = as.y + ad.y; l1 = l1 > 0.f ? l1 : 0.2f * l1;
    float l2 = as.z + ad.z; l2 = l2 > 0.f ? l2 : 0.2f * l2;
    float l3 = as.w + ad.w; l3 = l3 > 0.f ? l3 : 0.2f * l3;
    float4 o4;
    o4.x = __expf(l0 - mm.x) * ss.x;
    o4.y = __expf(l1 - mm.y) * ss.y;
    o4.z = __expf(l2 - mm.z) * ss.z;
    o4.w = __expf(l3 - mm.w) * ss.w;
    *(float4*)(out_alpha + (size_t)e * 4) = o4;
}

/* one wave per (t,dst): recompute alpha inline, accumulate over 4 heads,
   mean-heads, +bias, ELU, LayerNorm (64-lane wave reduction). */
__global__ __launch_bounds__(256) void k_accum1(const int* __restrict__ rowstart,
                                                const int* __restrict__ csr_src,
                                                const bf16* __restrict__ XW1b,
                                                const float* __restrict__ ALS1,
                                                const float* __restrict__ ALD1,
                                                const float* __restrict__ M1,
                                                const float* __restrict__ SI1,
                                                const float* __restrict__ b1,
                                                const float* __restrict__ ln_g,
                                                const float* __restrict__ ln_b,
                                                float* __restrict__ HS) {
    int wid = blockIdx.x * 4 + (threadIdx.x >> 6);
    int lane = threadIdx.x & 63;
    if (wid >= TN) return;
    int t = wid / N_NODES, n = wid % N_NODES;
    float4 ad = *(const float4*)(ALD1 + wid * 4);
    float4 m4 = *(const float4*)(M1 + wid * 4);
    float4 si = *(const float4*)(SI1 + wid * 4);
    int rs = rowstart[n], re = rowstart[n + 1];
    int tb = t * N_NODES;
    float acc = 0.f;
    for (int e = rs; e < re; e++) {
        int src = csr_src[e];
        float4 as = *(const float4*)(ALS1 + (tb + src) * 4);
        float l0 = as.x + ad.x; l0 = l0 > 0.f ? l0 : 0.2f * l0;
        float l1 = as.y + ad.y; l1 = l1 > 0.f ? l1 : 0.2f * l1;
        float l2 = as.z + ad.z; l2 = l2 > 0.f ? l2 : 0.2f * l2;
        float l3 = as.w + ad.w; l3 = l3 > 0.f ? l3 : 0.2f * l3;
        float a0 = __expf(l0 - m4.x) * si.x;
        float a1 = __expf(l1 - m4.y) * si.y;
        float a2 = __expf(l2 - m4.z) * si.z;
        float a3 = __expf(l3 - m4.w) * si.w;
        const unsigned* p = (const unsigned*)(XW1b + (size_t)(tb + src) * 256 + lane * 4);
        unsigned u0 = p[0], u1 = p[1];
        float x0 = __uint_as_float(u0 << 16);
        float x1 = __uint_as_float(u0 & 0xffff0000u);
        float x2 = __uint_as_float(u1 << 16);
        float x3 = __uint_as_float(u1 & 0xffff0000u);
        acc += a0 * x0 + a1 * x1 + a2 * x2 + a3 * x3;
    }
    float v = acc * 0.25f + b1[lane];
    v = v > 0.f ? v : (__expf(v) - 1.f);
    /* LayerNorm across the 64 lanes */
    float s = v;
#pragma unroll
    for (int o = 32; o; o >>= 1) s += __shfl_xor(s, o, 64);
    float mu = s * (1.f / 64.f);
    float d = v - mu;
    float q = d * d;
#pragma unroll
    for (int o = 32; o; o >>= 1) q += __shfl_xor(q, o, 64);
    float var = q * (1.f / 64.f);
    float y = d * rsqrtf(var + 1e-5f) * ln_g[lane] + ln_b[lane];
    HS[(size_t)wid * 64 + lane] = y;
}

/* ---------------- GRU ---------------- */

__global__ void k_zero(float* p, int nelem) {
    int i = blockIdx.x * blockDim.x + threadIdx.x;
    if (i < nelem) p[i] = 0.f;
}

/* block = 192 threads (one per gate-row j), 16 nodes per block.
   fp32 weight rows held in registers, reused across the 16 nodes. */
__global__ __launch_bounds__(192) void k_gru(int t,
                                             const float* __restrict__ HS,
                                             const float* __restrict__ W_ih,
                                             const float* __restrict__ W_hh,
                                             const float* __restrict__ b_ih,
                                             const float* __restrict__ b_hh,
                                             const float* __restrict__ Hprev,
                                             float* __restrict__ Hnew) {
    __shared__ float xs[64], hsv[64], gis[192], ghs[192];
    int j = threadIdx.x;
    float wi[64], wh[64];
    const float4* wi4 = (const float4*)(W_ih) + (size_t)j * 16;  // row j = 64 floats
    const float4* wh4 = (const float4*)(W_hh) + (size_t)j * 16;
#pragma unroll
    for (int q = 0; q < 16; q++) {
        float4 a = wi4[q];
        wi[q * 4 + 0] = a.x; wi[q * 4 + 1] = a.y; wi[q * 4 + 2] = a.z; wi[q * 4 + 3] = a.w;
        float4 b = wh4[q];
        wh[q * 4 + 0] = b.x; wh[q * 4 + 1] = b.y; wh[q * 4 + 2] = b.z; wh[q * 4 + 3] = b.w;
    }
    float bi = b_ih[j], bh = b_hh[j];
    for (int rr = 0; rr < 16; rr++) {
        int n = blockIdx.x * 16 + rr;
        if (j < 64) xs[j] = HS[((size_t)t * N_NODES + n) * 64 + j];
        else if (j < 128) hsv[j - 64] = Hprev[(size_t)n * 64 + (j - 64)];
        __syncthreads();
        float gi = bi, gh = bh;
#pragma unroll
        for (int k = 0; k < 64; k++) {
            gi += wi[k] * xs[k];
            gh += wh[k] * hsv[k];
        }
        gis[j] = gi; ghs[j] = gh;
        __syncthreads();
        if (j < 64) {
            float r = 1.f / (1.f + __expf(-(gis[j] + ghs[j])));
            float z = 1.f / (1.f + __expf(-(gis[64 + j] + ghs[64 + j])));
            float g = tanhf(gis[128 + j] + r * ghs[128 + j]);
            Hnew[(size_t)n * 64 + j] = (1.f - z) * g + z * hsv[j];
        }
        __syncthreads();
    }
}

/* ---------------- output writers (fp32) ---------------- */

__global__ void k_out_h(const float* __restrict__ H, float* __restrict__ out) {
    int i = blockIdx.x * blockDim.x + threadIdx.x;
    if (i < N_NODES * HID) out[i] = H[i];
}

__global__ void k_out_ei(const int* __restrict__ ei, float* __restrict__ out) {
    int i = blockIdx.x * blockDim.x + threadIdx.x;
    if (i >= 2 * EP) return;
    int v;
    if (i < EP) {
        v = (i < E_EDGES) ? ei[i] : (i - E_EDGES);                 // src row
    } else {
        int jj = i - EP;
        v = (jj < E_EDGES) ? ei[E_EDGES + jj] : (jj - E_EDGES);    // dst row
    }
    out[i] = (float)v;
}

/* ---------------- launch ---------------- */

extern "C" void kernel_launch(void* const* d_in, const int* in_sizes, int n_in,
                              void* d_out, int out_size, void* d_ws, size_t ws_size,
                              hipStream_t stream) {
    const float* x      = (const float*)d_in[0];
    const int*   ei     = (const int*)d_in[1];
    const float* W0     = (const float*)d_in[2];
    const float* a_src0 = (const float*)d_in[3];
    const float* a_dst0 = (const float*)d_in[4];
    const float* b0     = (const float*)d_in[5];
    const float* W1     = (const float*)d_in[6];
    const float* a_src1 = (const float*)d_in[7];
    const float* a_dst1 = (const float*)d_in[8];
    const float* b1     = (const float*)d_in[9];
    const float* ln_g   = (const float*)d_in[10];
    const float* ln_b   = (const float*)d_in[11];
    const float* W_ih   = (const float*)d_in[12];
    const float* W_hh   = (const float*)d_in[13];
    const float* b_ih   = (const float*)d_in[14];
    const float* b_hh   = (const float*)d_in[15];
    float* out = (float*)d_out;

    char* w = (char*)d_ws;
    size_t off = 0;
    auto take = [&](size_t bytes) -> void* {
        void* p = w + off;
        off = (off + bytes + 255) & ~(size_t)255;
        return p;
    };
    int*   counts  = (int*)take(N_NODES * 4);
    int*   fill    = (int*)take(N_NODES * 4);
    int*   rowst   = (int*)take((N_NODES + 1) * 4);
    int*   csr_src = (int*)take((size_t)EP * 4);
    bf16*  XW0b    = (bf16*)take((size_t)TN * 64 * 2);
    float* ALS0    = (float*)take((size_t)TN * 4 * 4);
    float* ALD0    = (float*)take((size_t)TN * 4 * 4);
    float* M0      = (float*)take((size_t)TN * 4 * 4);
    float* SI0     = (float*)take((size_t)TN * 4 * 4);
    bf16*  H0b     = (bf16*)take((size_t)TN * 64 * 2);
    bf16*  XW1b    = (bf16*)take((size_t)TN * 256 * 2);
    float* ALS1    = (float*)take((size_t)TN * 4 * 4);
    float* ALD1    = (float*)take((size_t)TN * 4 * 4);
    float* M1      = (float*)take((size_t)TN * 4 * 4);
    float* SI1     = (float*)take((size_t)TN * 4 * 4);
    float* HS      = (float*)take((size_t)TN * 64 * 4);
    float* HA      = (float*)take((size_t)N_NODES * 64 * 4);
    float* HB      = (float*)take((size_t)N_NODES * 64 * 4);
    (void)ws_size; (void)in_sizes; (void)n_in; (void)out_size;

    const int B = 256;
    /* CSR build */
    k_init<<<(N_NODES + B - 1) / B, B, 0, stream>>>(counts, fill);
    k_count<<<(EP + B - 1) / B, B, 0, stream>>>(ei, counts);
    k_scan<<<1, 1024, 0, stream>>>(counts, rowst);
    k_scatter<<<(EP + B - 1) / B, B, 0, stream>>>(ei, rowst, fill, csr_src);

    /* GAT layer 0 (all t batched) */
    k_gemm0<<<TN / 4, B, 0, stream>>>(x, W0, a_src0, a_dst0, XW0b, ALS0, ALD0);
    k_softmax<<<(TN * HEADS + B - 1) / B, B, 0, stream>>>(rowst, csr_src, ALS0, ALD0, M0, SI0);
    k_accum0<<<TN / 4, B, 0, stream>>>(rowst, csr_src, XW0b, ALS0, ALD0, M0, SI0, b0, H0b);

    /* GAT layer 1 (all t batched) */
    k_gemm1<<<TN / 16, B, 0, stream>>>(H0b, W1, a_src1, a_dst1, XW1b, ALS1, ALD1);
    k_softmax<<<(TN * HEADS + B - 1) / B, B, 0, stream>>>(rowst, csr_src, ALS1, ALD1, M1, SI1);
    k_alpha_out<<<(EP + B - 1) / B, B, 0, stream>>>(ei, ALS1, ALD1, M1, SI1,
                                                    out + (size_t)N_NODES * HID);
    k_accum1<<<TN / 4, B, 0, stream>>>(rowst, csr_src, XW1b, ALS1, ALD1, M1, SI1,
                                       b1, ln_g, ln_b, HS);

    /* GRU over T steps */
    k_zero<<<(N_NODES * 64 + B - 1) / B, B, 0, stream>>>(HA, N_NODES * 64);
    float* hbuf[2] = { HA, HB };
    for (int t = 0; t < T_STEPS; t++) {
        float* prev = hbuf[t & 1];
        float* next = hbuf[1 - (t & 1)];
        k_gru<<<N_NODES / 16, 192, 0, stream>>>(t, HS, W_ih, W_hh, b_ih, b_hh, prev, next);
    }
    /* after 6 steps final h is in HA */

    /* outputs (fp32): [hT (640000)] [alpha_last (680000)] [edge_index (340000)] */
    k_out_h<<<(N_NODES * HID + B - 1) / B, B, 0, stream>>>(HA, out);
    k_out_ei<<<(2 * EP + B - 1) / B, B, 0, stream>>>(ei, out + (size_t)N_NODES * HID + (size_t)EP * HEADS);
}

// Round 4
// 693.456 us; speedup vs baseline: 1.0110x; 1.0110x over previous
//
#include <hip/hip_runtime.h>
#include <hip/hip_bf16.h>
#include <cstdint>
#include <cstddef>

#define N_NODES 10000
#define T_STEPS 6
#define F_IN    64
#define HID     64
#define HEADS   4
#define E_EDGES 160000
#define EP      (E_EDGES + N_NODES)   /* 170000 edges incl self-loops */
#define TN      (T_STEPS * N_NODES)   /* 60000 */
#define TEP     (T_STEPS * EP)        /* 1020000 */

typedef __hip_bfloat16 bf16;

__device__ __forceinline__ float b2f(bf16 v) { return __bfloat162float(v); }

/* ---------------- CSR build ---------------- */

__global__ void k_init(int* counts, int* fill) {
    int i = blockIdx.x * blockDim.x + threadIdx.x;
    if (i < N_NODES) { counts[i] = 0; fill[i] = 0; }
}

__global__ void k_count(const int* ei, int* counts) {
    int e = blockIdx.x * blockDim.x + threadIdx.x;
    if (e >= EP) return;
    int dst = (e < E_EDGES) ? ei[E_EDGES + e] : (e - E_EDGES);
    atomicAdd(&counts[dst], 1);
}

__global__ void k_scan(const int* counts, int* rowstart) {
    __shared__ int part[1024];
    int tid = threadIdx.x;
    const int chunk = (N_NODES + 1023) / 1024;  // 10
    int base = tid * chunk;
    int s = 0;
    for (int i = 0; i < chunk; i++) { int idx = base + i; if (idx < N_NODES) s += counts[idx]; }
    part[tid] = s;
    __syncthreads();
    for (int off = 1; off < 1024; off <<= 1) {
        int v = (tid >= off) ? part[tid - off] : 0;
        __syncthreads();
        part[tid] += v;
        __syncthreads();
    }
    int run = (tid == 0) ? 0 : part[tid - 1];
    for (int i = 0; i < chunk; i++) {
        int idx = base + i;
        if (idx < N_NODES) { rowstart[idx] = run; run += counts[idx]; }
    }
    if (tid == 0) rowstart[N_NODES] = EP;
}

__global__ void k_scatter(const int* ei, const int* rowstart, int* fill,
                          int* csr_src, int* csr_dst) {
    int e = blockIdx.x * blockDim.x + threadIdx.x;
    if (e >= EP) return;
    int src = (e < E_EDGES) ? ei[e] : (e - E_EDGES);
    int dst = (e < E_EDGES) ? ei[E_EDGES + e] : (e - E_EDGES);
    int pos = rowstart[dst] + atomicAdd(&fill[dst], 1);
    csr_src[pos] = src;
    csr_dst[pos] = dst;
}

/* ---------------- GAT layer 0 ---------------- */

/* X[60000,64] @ W0[64,64] -> XW0 (bf16), + fused per-row attention logits
   (fp32 accumulator). 256 threads = 4 rows x 64 cols; one wave per row. */
__global__ __launch_bounds__(256) void k_gemm0(const float* __restrict__ x,
                                               const float* __restrict__ W0,
                                               const float* __restrict__ a_src0,
                                               const float* __restrict__ a_dst0,
                                               bf16* __restrict__ XW0b,
                                               float* __restrict__ ALS0,
                                               float* __restrict__ ALD0) {
    __shared__ float wl[64 * 64];
    __shared__ float xl[4][64];
    int tid = threadIdx.x;
    for (int i = tid; i < 4096; i += 256) wl[i] = W0[i];
    int r = tid >> 6, c = tid & 63;
    int row = blockIdx.x * 4 + r;            // row = t*N + n
    int t = row / N_NODES, n = row % N_NODES;
    xl[r][c] = x[(size_t)(n * T_STEPS + t) * F_IN + c];  // x is [N,T,F]
    __syncthreads();
    float acc = 0.f;
#pragma unroll
    for (int k = 0; k < 64; k++) acc += xl[r][k] * wl[k * 64 + c];
    XW0b[(size_t)row * 64 + c] = __float2bfloat16(acc);
    int h = c >> 4, cc = c & 15;
    float ps = acc * a_src0[h * 16 + cc];
    float pd = acc * a_dst0[h * 16 + cc];
#pragma unroll
    for (int o = 8; o; o >>= 1) { ps += __shfl_xor(ps, o, 64); pd += __shfl_xor(pd, o, 64); }
    if (cc == 0) { ALS0[row * 4 + h] = ps; ALD0[row * 4 + h] = pd; }
}

/* wave-parallel segment softmax: one wave per (t,n); lanes parallel over
   edges; butterfly max/sum over 64 lanes for all 4 heads at once. */
__global__ __launch_bounds__(256) void k_softmax_wave(const int* __restrict__ rowstart,
                                                      const int* __restrict__ csr_src,
                                                      const float* __restrict__ ALS,
                                                      const float* __restrict__ ALD,
                                                      float* __restrict__ M,
                                                      float* __restrict__ SI) {
    int wid = blockIdx.x * 4 + (threadIdx.x >> 6);
    int lane = threadIdx.x & 63;
    if (wid >= TN) return;
    int t = wid / N_NODES, n = wid % N_NODES;
    int rs = rowstart[n], re = rowstart[n + 1];
    int tb = t * N_NODES;
    float4 ad = *(const float4*)(ALD + (size_t)wid * 4);
    float m0 = -1e30f, m1 = -1e30f, m2 = -1e30f, m3 = -1e30f;
    for (int e = rs + lane; e < re; e += 64) {
        int src = csr_src[e];
        float4 as = *(const float4*)(ALS + (size_t)(tb + src) * 4);
        float l0 = as.x + ad.x; l0 = l0 > 0.f ? l0 : 0.2f * l0; m0 = fmaxf(m0, l0);
        float l1 = as.y + ad.y; l1 = l1 > 0.f ? l1 : 0.2f * l1; m1 = fmaxf(m1, l1);
        float l2 = as.z + ad.z; l2 = l2 > 0.f ? l2 : 0.2f * l2; m2 = fmaxf(m2, l2);
        float l3 = as.w + ad.w; l3 = l3 > 0.f ? l3 : 0.2f * l3; m3 = fmaxf(m3, l3);
    }
#pragma unroll
    for (int o = 32; o; o >>= 1) {
        m0 = fmaxf(m0, __shfl_xor(m0, o, 64));
        m1 = fmaxf(m1, __shfl_xor(m1, o, 64));
        m2 = fmaxf(m2, __shfl_xor(m2, o, 64));
        m3 = fmaxf(m3, __shfl_xor(m3, o, 64));
    }
    float s0 = 0.f, s1 = 0.f, s2 = 0.f, s3 = 0.f;
    for (int e = rs + lane; e < re; e += 64) {
        int src = csr_src[e];
        float4 as = *(const float4*)(ALS + (size_t)(tb + src) * 4);
        float l0 = as.x + ad.x; l0 = l0 > 0.f ? l0 : 0.2f * l0; s0 += __expf(l0 - m0);
        float l1 = as.y + ad.y; l1 = l1 > 0.f ? l1 : 0.2f * l1; s1 += __expf(l1 - m1);
        float l2 = as.z + ad.z; l2 = l2 > 0.f ? l2 : 0.2f * l2; s2 += __expf(l2 - m2);
        float l3 = as.w + ad.w; l3 = l3 > 0.f ? l3 : 0.2f * l3; s3 += __expf(l3 - m3);
    }
#pragma unroll
    for (int o = 32; o; o >>= 1) {
        s0 += __shfl_xor(s0, o, 64);
        s1 += __shfl_xor(s1, o, 64);
        s2 += __shfl_xor(s2, o, 64);
        s3 += __shfl_xor(s3, o, 64);
    }
    if (lane == 0) {
        float4 m4; m4.x = m0; m4.y = m1; m4.z = m2; m4.w = m3;
        float4 si; si.x = 1.f / (s0 + 1e-16f); si.y = 1.f / (s1 + 1e-16f);
        si.z = 1.f / (s2 + 1e-16f); si.w = 1.f / (s3 + 1e-16f);
        *(float4*)(M + (size_t)wid * 4) = m4;
        *(float4*)(SI + (size_t)wid * 4) = si;
    }
}

/* per-(t, CSR-pos) alpha, all 4 heads, stored in CSR order as float4.
   One thread per (t,pos) — no wave redundancy. */
__global__ void k_alpha_csr(const int* __restrict__ csr_src, const int* __restrict__ csr_dst,
                            const float* __restrict__ ALS, const float* __restrict__ ALD,
                            const float* __restrict__ M, const float* __restrict__ SI,
                            float* __restrict__ ALPHA) {
    int idx = blockIdx.x * blockDim.x + threadIdx.x;
    if (idx >= TEP) return;
    int t = idx / EP, pos = idx - t * EP;
    int src = csr_src[pos], dst = csr_dst[pos];
    int tb = t * N_NODES;
    float4 as = *(const float4*)(ALS + (size_t)(tb + src) * 4);
    float4 ad = *(const float4*)(ALD + (size_t)(tb + dst) * 4);
    float4 mm = *(const float4*)(M + (size_t)(tb + dst) * 4);
    float4 ss = *(const float4*)(SI + (size_t)(tb + dst) * 4);
    float l0 = as.x + ad.x; l0 = l0 > 0.f ? l0 : 0.2f * l0;
    float l1 = as.y + ad.y; l1 = l1 > 0.f ? l1 : 0.2f * l1;
    float l2 = as.z + ad.z; l2 = l2 > 0.f ? l2 : 0.2f * l2;
    float l3 = as.w + ad.w; l3 = l3 > 0.f ? l3 : 0.2f * l3;
    float4 o4;
    o4.x = __expf(l0 - mm.x) * ss.x;
    o4.y = __expf(l1 - mm.y) * ss.y;
    o4.z = __expf(l2 - mm.z) * ss.z;
    o4.w = __expf(l3 - mm.w) * ss.w;
    *(float4*)(ALPHA + (size_t)idx * 4) = o4;
}

/* one wave per (t,dst): alpha-weighted accumulate (alpha precomputed), +bias, ELU */
__global__ __launch_bounds__(256) void k_accum0(const int* __restrict__ rowstart,
                                                const int* __restrict__ csr_src,
                                                const bf16* __restrict__ XW0b,
                                                const float* __restrict__ ALPHA0,
                                                const float* __restrict__ b0,
                                                bf16* __restrict__ H0b) {
    int wid = blockIdx.x * 4 + (threadIdx.x >> 6);
    int lane = threadIdx.x & 63;
    if (wid >= TN) return;
    int t = wid / N_NODES, n = wid % N_NODES;
    int h = lane >> 4;
    int rs = rowstart[n], re = rowstart[n + 1];
    int tb = t * N_NODES;
    size_t ab = (size_t)t * EP;
    float acc = 0.f;
    for (int e = rs; e < re; e++) {
        int src = csr_src[e];
        float a = ALPHA0[(ab + e) * 4 + h];
        acc += b2f(XW0b[(size_t)(tb + src) * 64 + lane]) * a;
    }
    float v = acc + b0[lane];
    v = v > 0.f ? v : (__expf(v) - 1.f);
    H0b[(size_t)wid * 64 + lane] = __float2bfloat16(v);
}

/* ---------------- GAT layer 1 ---------------- */

/* H0[60000,64] @ W1[64,256] -> XW1 (bf16, head-interleaved [cc][h] layout)
   + fused logits. 16 rows per block, W1 cached in LDS as bf16 (32 KB). */
__global__ __launch_bounds__(256) void k_gemm1(const bf16* __restrict__ H0b,
                                               const float* __restrict__ W1,
                                               const float* __restrict__ a_src1,
                                               const float* __restrict__ a_dst1,
                                               bf16* __restrict__ XW1b,
                                               float* __restrict__ ALS1,
                                               float* __restrict__ ALD1) {
    __shared__ bf16 wl[64 * 256];
    __shared__ float hl[16][64];
    int tid = threadIdx.x;
    for (int i = tid; i < 64 * 256; i += 256) wl[i] = __float2bfloat16(W1[i]);
    int rbase = blockIdx.x * 16;
    for (int i = tid; i < 16 * 64; i += 256)
        hl[i >> 6][i & 63] = b2f(H0b[((size_t)rbase + (i >> 6)) * 64 + (i & 63)]);
    __syncthreads();
    int h = tid >> 6, cc = tid & 63;
    float as = a_src1[h * 64 + cc], ad = a_dst1[h * 64 + cc];
    for (int r = 0; r < 16; r++) {
        float acc = 0.f;
#pragma unroll
        for (int k = 0; k < 64; k++) acc += hl[r][k] * b2f(wl[k * 256 + tid]);
        int row = rbase + r;
        /* head-interleaved store: row*256 + cc*4 + h */
        XW1b[(size_t)row * 256 + cc * 4 + h] = __float2bfloat16(acc);
        float ps = acc * as;
        float pd = acc * ad;
#pragma unroll
        for (int o = 32; o; o >>= 1) { ps += __shfl_xor(ps, o, 64); pd += __shfl_xor(pd, o, 64); }
        if (cc == 0) { ALS1[row * 4 + h] = ps; ALD1[row * 4 + h] = pd; }
    }
}

/* alpha output for t = T-1 only, in ORIGINAL edge order -> fp32 out */
__global__ void k_alpha_out(const int* __restrict__ ei,
                            const float* __restrict__ ALS1, const float* __restrict__ ALD1,
                            const float* __restrict__ M1, const float* __restrict__ SI1,
                            float* __restrict__ out_alpha) {
    int e = blockIdx.x * blockDim.x + threadIdx.x;
    if (e >= EP) return;
    int src = (e < E_EDGES) ? ei[e] : (e - E_EDGES);
    int dst = (e < E_EDGES) ? ei[E_EDGES + e] : (e - E_EDGES);
    const int tb = (T_STEPS - 1) * N_NODES;
    int sb = (tb + src) * 4, db = (tb + dst) * 4;
    float4 as = *(const float4*)(ALS1 + sb);
    float4 ad = *(const float4*)(ALD1 + db);
    float4 mm = *(const float4*)(M1 + db);
    float4 ss = *(const float4*)(SI1 + db);
    float l0 = as.x + ad.x; l0 = l0 > 0.f ? l0 : 0.2f * l0;
    float l1 = as.y + ad.y; l1 = l1 > 0.f ? l1 : 0.2f * l1;
    float l2 = as.z + ad.z; l2 = l2 > 0.f ? l2 : 0.2f * l2;
    float l3 = as.w + ad.w; l3 = l3 > 0.f ? l3 : 0.2f * l3;
    float4 o4;
    o4.x = __expf(l0 - mm.x) * ss.x;
    o4.y = __expf(l1 - mm.y) * ss.y;
    o4.z = __expf(l2 - mm.z) * ss.z;
    o4.w = __expf(l3 - mm.w) * ss.w;
    *(float4*)(out_alpha + (size_t)e * 4) = o4;
}

/* one wave per (t,dst): alpha precomputed; accumulate 4 heads, mean-heads,
   +bias, ELU, LayerNorm. */
__global__ __launch_bounds__(256) void k_accum1(const int* __restrict__ rowstart,
                                                const int* __restrict__ csr_src,
                                                const bf16* __restrict__ XW1b,
                                                const float* __restrict__ ALPHA1,
                                                const float* __restrict__ b1,
                                                const float* __restrict__ ln_g,
                                                const float* __restrict__ ln_b,
                                                float* __restrict__ HS) {
    int wid = blockIdx.x * 4 + (threadIdx.x >> 6);
    int lane = threadIdx.x & 63;
    if (wid >= TN) return;
    int t = wid / N_NODES, n = wid % N_NODES;
    int rs = rowstart[n], re = rowstart[n + 1];
    int tb = t * N_NODES;
    size_t ab = (size_t)t * EP;
    float acc = 0.f;
    for (int e = rs; e < re; e++) {
        int src = csr_src[e];
        float4 al = *(const float4*)(ALPHA1 + (ab + e) * 4);
        const unsigned* p = (const unsigned*)(XW1b + (size_t)(tb + src) * 256 + lane * 4);
        unsigned u0 = p[0], u1 = p[1];
        float x0 = __uint_as_float(u0 << 16);
        float x1 = __uint_as_float(u0 & 0xffff0000u);
        float x2 = __uint_as_float(u1 << 16);
        float x3 = __uint_as_float(u1 & 0xffff0000u);
        acc += al.x * x0 + al.y * x1 + al.z * x2 + al.w * x3;
    }
    float v = acc * 0.25f + b1[lane];
    v = v > 0.f ? v : (__expf(v) - 1.f);
    /* LayerNorm across the 64 lanes */
    float s = v;
#pragma unroll
    for (int o = 32; o; o >>= 1) s += __shfl_xor(s, o, 64);
    float mu = s * (1.f / 64.f);
    float d = v - mu;
    float q = d * d;
#pragma unroll
    for (int o = 32; o; o >>= 1) q += __shfl_xor(q, o, 64);
    float var = q * (1.f / 64.f);
    float y = d * rsqrtf(var + 1e-5f) * ln_g[lane] + ln_b[lane];
    HS[(size_t)wid * 64 + lane] = y;
}

/* ---------------- GRU ---------------- */

__global__ void k_zero(float* p, int nelem) {
    int i = blockIdx.x * blockDim.x + threadIdx.x;
    if (i < nelem) p[i] = 0.f;
}

/* non-recurrent half: GI[t,n,j] = b_ih[j] + dot(W_ih[j], HS[t,n]) for all t.
   192 threads (one per gate-row), 16 rows/block; weights in VGPRs. */
__global__ __launch_bounds__(192) void k_gi(const float* __restrict__ HS,
                                            const float* __restrict__ W_ih,
                                            const float* __restrict__ b_ih,
                                            bf16* __restrict__ GIb) {
    __shared__ float xs[64];
    int j = threadIdx.x;
    float wi[64];
    const float4* wi4 = (const float4*)(W_ih) + (size_t)j * 16;
#pragma unroll
    for (int q = 0; q < 16; q++) {
        float4 a = wi4[q];
        wi[q * 4 + 0] = a.x; wi[q * 4 + 1] = a.y; wi[q * 4 + 2] = a.z; wi[q * 4 + 3] = a.w;
    }
    float bi = b_ih[j];
    for (int rr = 0; rr < 16; rr++) {
        int row = blockIdx.x * 16 + rr;
        if (j < 64) xs[j] = HS[(size_t)row * 64 + j];
        __syncthreads();
        float gi = bi;
#pragma unroll
        for (int k = 0; k < 64; k++) gi += wi[k] * xs[k];
        GIb[(size_t)row * 192 + j] = __float2bfloat16(gi);
        __syncthreads();
    }
}

/* recurrent half: gh = b_hh + W_hh@h, combine with precomputed GI. */
__global__ __launch_bounds__(192) void k_gru_step(int t,
                                                  const bf16* __restrict__ GIb,
                                                  const float* __restrict__ W_hh,
                                                  const float* __restrict__ b_hh,
                                                  const float* __restrict__ Hprev,
                                                  float* __restrict__ Hnew) {
    __shared__ float hsv[64], gis[192], ghs[192];
    int j = threadIdx.x;
    float wh[64];
    const float4* wh4 = (const float4*)(W_hh) + (size_t)j * 16;
#pragma unroll
    for (int q = 0; q < 16; q++) {
        float4 b = wh4[q];
        wh[q * 4 + 0] = b.x; wh[q * 4 + 1] = b.y; wh[q * 4 + 2] = b.z; wh[q * 4 + 3] = b.w;
    }
    float bh = b_hh[j];
    for (int rr = 0; rr < 16; rr++) {
        int n = blockIdx.x * 16 + rr;
        if (j < 64) hsv[j] = Hprev[(size_t)n * 64 + j];
        __syncthreads();
        float gh = bh;
#pragma unroll
        for (int k = 0; k < 64; k++) gh += wh[k] * hsv[k];
        gis[j] = b2f(GIb[((size_t)t * N_NODES + n) * 192 + j]);
        ghs[j] = gh;
        __syncthreads();
        if (j < 64) {
            float r = 1.f / (1.f + __expf(-(gis[j] + ghs[j])));
            float z = 1.f / (1.f + __expf(-(gis[64 + j] + ghs[64 + j])));
            float g = tanhf(gis[128 + j] + r * ghs[128 + j]);
            Hnew[(size_t)n * 64 + j] = (1.f - z) * g + z * hsv[j];
        }
        __syncthreads();
    }
}

/* ---------------- output writers (fp32) ---------------- */

__global__ void k_out_h(const float* __restrict__ H, float* __restrict__ out) {
    int i = blockIdx.x * blockDim.x + threadIdx.x;
    if (i < N_NODES * HID) out[i] = H[i];
}

__global__ void k_out_ei(const int* __restrict__ ei, float* __restrict__ out) {
    int i = blockIdx.x * blockDim.x + threadIdx.x;
    if (i >= 2 * EP) return;
    int v;
    if (i < EP) {
        v = (i < E_EDGES) ? ei[i] : (i - E_EDGES);                 // src row
    } else {
        int jj = i - EP;
        v = (jj < E_EDGES) ? ei[E_EDGES + jj] : (jj - E_EDGES);    // dst row
    }
    out[i] = (float)v;
}

/* ---------------- launch ---------------- */

extern "C" void kernel_launch(void* const* d_in, const int* in_sizes, int n_in,
                              void* d_out, int out_size, void* d_ws, size_t ws_size,
                              hipStream_t stream) {
    const float* x      = (const float*)d_in[0];
    const int*   ei     = (const int*)d_in[1];
    const float* W0     = (const float*)d_in[2];
    const float* a_src0 = (const float*)d_in[3];
    const float* a_dst0 = (const float*)d_in[4];
    const float* b0     = (const float*)d_in[5];
    const float* W1     = (const float*)d_in[6];
    const float* a_src1 = (const float*)d_in[7];
    const float* a_dst1 = (const float*)d_in[8];
    const float* b1     = (const float*)d_in[9];
    const float* ln_g   = (const float*)d_in[10];
    const float* ln_b   = (const float*)d_in[11];
    const float* W_ih   = (const float*)d_in[12];
    const float* W_hh   = (const float*)d_in[13];
    const float* b_ih   = (const float*)d_in[14];
    const float* b_hh   = (const float*)d_in[15];
    float* out = (float*)d_out;

    char* w = (char*)d_ws;
    size_t off = 0;
    auto take = [&](size_t bytes) -> void* {
        void* p = w + off;
        off = (off + bytes + 255) & ~(size_t)255;
        return p;
    };
    int*   counts  = (int*)take(N_NODES * 4);
    int*   fill    = (int*)take(N_NODES * 4);
    int*   rowst   = (int*)take((N_NODES + 1) * 4);
    int*   csr_src = (int*)take((size_t)EP * 4);
    int*   csr_dst = (int*)take((size_t)EP * 4);
    bf16*  XW0b    = (bf16*)take((size_t)TN * 64 * 2);
    float* ALS0    = (float*)take((size_t)TN * 4 * 4);
    float* ALD0    = (float*)take((size_t)TN * 4 * 4);
    float* M0      = (float*)take((size_t)TN * 4 * 4);
    float* SI0     = (float*)take((size_t)TN * 4 * 4);
    float* ALPHA0  = (float*)take((size_t)TEP * 4 * 4);
    bf16*  H0b     = (bf16*)take((size_t)TN * 64 * 2);
    bf16*  XW1b    = (bf16*)take((size_t)TN * 256 * 2);
    float* ALS1    = (float*)take((size_t)TN * 4 * 4);
    float* ALD1    = (float*)take((size_t)TN * 4 * 4);
    float* M1      = (float*)take((size_t)TN * 4 * 4);
    float* SI1     = (float*)take((size_t)TN * 4 * 4);
    float* ALPHA1  = (float*)take((size_t)TEP * 4 * 4);
    float* HS      = (float*)take((size_t)TN * 64 * 4);
    bf16*  GIb     = (bf16*)take((size_t)TN * 192 * 2);
    float* HA      = (float*)take((size_t)N_NODES * 64 * 4);
    float* HB      = (float*)take((size_t)N_NODES * 64 * 4);
    (void)ws_size; (void)in_sizes; (void)n_in; (void)out_size;

    const int B = 256;
    /* CSR build */
    k_init<<<(N_NODES + B - 1) / B, B, 0, stream>>>(counts, fill);
    k_count<<<(EP + B - 1) / B, B, 0, stream>>>(ei, counts);
    k_scan<<<1, 1024, 0, stream>>>(counts, rowst);
    k_scatter<<<(EP + B - 1) / B, B, 0, stream>>>(ei, rowst, fill, csr_src, csr_dst);

    /* GAT layer 0 (all t batched) */
    k_gemm0<<<TN / 4, B, 0, stream>>>(x, W0, a_src0, a_dst0, XW0b, ALS0, ALD0);
    k_softmax_wave<<<TN / 4, B, 0, stream>>>(rowst, csr_src, ALS0, ALD0, M0, SI0);
    k_alpha_csr<<<(TEP + B - 1) / B, B, 0, stream>>>(csr_src, csr_dst, ALS0, ALD0, M0, SI0, ALPHA0);
    k_accum0<<<TN / 4, B, 0, stream>>>(rowst, csr_src, XW0b, ALPHA0, b0, H0b);

    /* GAT layer 1 (all t batched) */
    k_gemm1<<<TN / 16, B, 0, stream>>>(H0b, W1, a_src1, a_dst1, XW1b, ALS1, ALD1);
    k_softmax_wave<<<TN / 4, B, 0, stream>>>(rowst, csr_src, ALS1, ALD1, M1, SI1);
    k_alpha_csr<<<(TEP + B - 1) / B, B, 0, stream>>>(csr_src, csr_dst, ALS1, ALD1, M1, SI1, ALPHA1);
    k_alpha_out<<<(EP + B - 1) / B, B, 0, stream>>>(ei, ALS1, ALD1, M1, SI1,
                                                    out + (size_t)N_NODES * HID);
    k_accum1<<<TN / 4, B, 0, stream>>>(rowst, csr_src, XW1b, ALPHA1, b1, ln_g, ln_b, HS);

    /* GRU: non-recurrent half batched over all t, then 6 sequential steps */
    k_gi<<<TN / 16, 192, 0, stream>>>(HS, W_ih, b_ih, GIb);
    k_zero<<<(N_NODES * 64 + B - 1) / B, B, 0, stream>>>(HA, N_NODES * 64);
    float* hbuf[2] = { HA, HB };
    for (int t = 0; t < T_STEPS; t++) {
        float* prev = hbuf[t & 1];
        float* next = hbuf[1 - (t & 1)];
        k_gru_step<<<N_NODES / 16, 192, 0, stream>>>(t, GIb, W_hh, b_hh, prev, next);
    }
    /* after 6 steps final h is in HA */

    /* outputs (fp32): [hT (640000)] [alpha_last (680000)] [edge_index (340000)] */
    k_out_h<<<(N_NODES * HID + B - 1) / B, B, 0, stream>>>(HA, out);
    k_out_ei<<<(2 * EP + B - 1) / B, B, 0, stream>>>(ei, out + (size_t)N_NODES * HID + (size_t)EP * HEADS);
}